// Round 1
// baseline (653.767 us; speedup 1.0000x reference)
//
#include <hip/hip_runtime.h>

// Problem constants (fixed by the reference):
#define NB 4
#define NN 50000
#define NE 800000
#define NF 128

#define TILE_M 128
#define KC 64

// ---------------------------------------------------------------------------
// GEMM: h[m][o] = sum_f x[m][f] * W[o][f]   (h = x @ W^T)
// 256 threads/block, 128 rows/block, 8x8 outputs per thread.
// K chunked at 64 so LDS = xT[64][128] + wT[64][128] = 64 KiB exactly.
// Inner-loop LDS reads are <=2-way bank aliased (free) because each thread
// owns rows {ry*4..+3, 64+ry*4..+3} and cols {cx*4..+3, 64+cx*4..+3}.
// ---------------------------------------------------------------------------
__global__ __launch_bounds__(256) void gemm_kernel(
    const float* __restrict__ x,   // [M][NF]
    const float* __restrict__ W,   // [NF][NF] (row = out feature)
    float* __restrict__ h,         // [M][NF]
    int M)
{
    __shared__ __align__(16) float xT[KC][TILE_M]; // [k][row]
    __shared__ __align__(16) float wT[KC][NF];     // [k][o]

    const int tid = threadIdx.x;
    const int cx  = tid & 15;   // col group 0..15
    const int ry  = tid >> 4;   // row group 0..15
    const int m0  = blockIdx.x * TILE_M;

    float acc[8][8];
#pragma unroll
    for (int i = 0; i < 8; ++i)
#pragma unroll
        for (int j = 0; j < 8; ++j) acc[i][j] = 0.f;

    for (int c = 0; c < NF; c += KC) {
        __syncthreads();
        // stage W chunk transposed: wT[k][o] = W[o][c+k]
#pragma unroll
        for (int it = 0; it < 8; ++it) {
            int linear = it * 256 + tid;     // 0..2047
            int o = linear >> 4;             // 0..127
            int q = linear & 15;             // float4 index in chunk
            float4 w4 = *(const float4*)(W + (size_t)o * NF + c + q * 4);
            wT[q * 4 + 0][o] = w4.x;
            wT[q * 4 + 1][o] = w4.y;
            wT[q * 4 + 2][o] = w4.z;
            wT[q * 4 + 3][o] = w4.w;
        }
        // stage x chunk transposed: xT[k][r] = x[m0+r][c+k]
#pragma unroll
        for (int it = 0; it < 8; ++it) {
            int linear = it * 256 + tid;
            int r = linear >> 4;             // 0..127
            int q = linear & 15;
            int gr = m0 + r;
            float4 v4 = make_float4(0.f, 0.f, 0.f, 0.f);
            if (gr < M) v4 = *(const float4*)(x + (size_t)gr * NF + c + q * 4);
            xT[q * 4 + 0][r] = v4.x;
            xT[q * 4 + 1][r] = v4.y;
            xT[q * 4 + 2][r] = v4.z;
            xT[q * 4 + 3][r] = v4.w;
        }
        __syncthreads();

#pragma unroll 2
        for (int k = 0; k < KC; ++k) {
            float4 a0 = *(const float4*)&xT[k][ry * 4];
            float4 a1 = *(const float4*)&xT[k][64 + ry * 4];
            float4 b0 = *(const float4*)&wT[k][cx * 4];
            float4 b1 = *(const float4*)&wT[k][64 + cx * 4];
            float a[8] = {a0.x, a0.y, a0.z, a0.w, a1.x, a1.y, a1.z, a1.w};
            float b[8] = {b0.x, b0.y, b0.z, b0.w, b1.x, b1.y, b1.z, b1.w};
#pragma unroll
            for (int i = 0; i < 8; ++i)
#pragma unroll
                for (int j = 0; j < 8; ++j)
                    acc[i][j] += a[i] * b[j];
        }
    }

    // store: rows {ry*4+i, 64+ry*4+i}, cols {cx*4..+3, 64+cx*4..+3}
#pragma unroll
    for (int i = 0; i < 8; ++i) {
        int r  = (i < 4) ? (ry * 4 + i) : (64 + ry * 4 + (i - 4));
        int gr = m0 + r;
        if (gr < M) {
            float4 s0 = make_float4(acc[i][0], acc[i][1], acc[i][2], acc[i][3]);
            float4 s1 = make_float4(acc[i][4], acc[i][5], acc[i][6], acc[i][7]);
            *(float4*)(h + (size_t)gr * NF + cx * 4)      = s0;
            *(float4*)(h + (size_t)gr * NF + 64 + cx * 4) = s1;
        }
    }
}

// ---------------------------------------------------------------------------
// CSR build: histogram -> exclusive scan -> stable-ish scatter
// ---------------------------------------------------------------------------
__global__ void hist_kernel(const int* __restrict__ row, int* __restrict__ cnt)
{
    int e = blockIdx.x * 256 + threadIdx.x;
    if (e < NE) atomicAdd(&cnt[row[e]], 1);
}

__global__ __launch_bounds__(1024) void scan_kernel(
    const int* __restrict__ cnt, int* __restrict__ rs)
{
    __shared__ int wsum[16];
    __shared__ int carry_s;
    const int tid  = threadIdx.x;
    const int lane = tid & 63;
    const int wid  = tid >> 6;
    if (tid == 0) carry_s = 0;
    __syncthreads();

    for (int base = 0; base < NN; base += 1024) {
        int i = base + tid;
        int v = (i < NN) ? cnt[i] : 0;
        int incl = v;
#pragma unroll
        for (int off = 1; off < 64; off <<= 1) {
            int t = __shfl_up(incl, off, 64);
            if (lane >= off) incl += t;
        }
        if (lane == 63) wsum[wid] = incl;
        __syncthreads();
        int woff = 0;
        for (int w = 0; w < wid; ++w) woff += wsum[w];
        if (i < NN) rs[i] = carry_s + woff + incl - v;   // exclusive
        __syncthreads();
        if (tid == 0) {
            int tot = 0;
            for (int w = 0; w < 16; ++w) tot += wsum[w];
            carry_s += tot;
        }
        __syncthreads();
    }
    if (tid == 0) rs[NN] = carry_s;   // == NE
}

__global__ void scatter_kernel(const int* __restrict__ row,
                               const int* __restrict__ col,
                               const float* __restrict__ val,
                               const int* __restrict__ rs,
                               int* __restrict__ cursor,
                               int* __restrict__ col_s,
                               float* __restrict__ val_s)
{
    int e = blockIdx.x * 256 + threadIdx.x;
    if (e < NE) {
        int r   = row[e];
        int p   = atomicAdd(&cursor[r], 1);
        int dst = rs[r] + p;
        col_s[dst] = col[e];
        val_s[dst] = val[e];
    }
}

// ---------------------------------------------------------------------------
// SpMM: one block (128 threads) per output row; thread t owns feature t.
// 4 batch accumulators per thread; per edge: 512 B coalesced gather per batch.
// Fully overwrites d_out (poison-safe), no atomics.
// ---------------------------------------------------------------------------
__global__ __launch_bounds__(128) void spmm_kernel(
    const float* __restrict__ h,
    const int* __restrict__ rs,
    const int* __restrict__ col_s,
    const float* __restrict__ val_s,
    float* __restrict__ out)
{
    const int r = blockIdx.x;
    const int t = threadIdx.x;
    const int s = rs[r];
    const int e = rs[r + 1];

    const size_t bstride = (size_t)NN * NF;
    float acc0 = 0.f, acc1 = 0.f, acc2 = 0.f, acc3 = 0.f;

    for (int i = s; i < e; ++i) {
        int   c = col_s[i];
        float v = val_s[i];
        const float* hp = h + (size_t)c * NF + t;
        acc0 += v * hp[0];
        acc1 += v * hp[bstride];
        acc2 += v * hp[2 * bstride];
        acc3 += v * hp[3 * bstride];
    }
    float* op = out + (size_t)r * NF + t;
    op[0]           = acc0;
    op[bstride]     = acc1;
    op[2 * bstride] = acc2;
    op[3 * bstride] = acc3;
}

// ---------------------------------------------------------------------------
extern "C" void kernel_launch(void* const* d_in, const int* in_sizes, int n_in,
                              void* d_out, int out_size, void* d_ws, size_t ws_size,
                              hipStream_t stream)
{
    const float* x    = (const float*)d_in[0];
    const float* W    = (const float*)d_in[1];
    const int*   erow = (const int*)d_in[2];
    const int*   ecol = (const int*)d_in[3];
    const float* ev   = (const float*)d_in[4];
    float*       out  = (float*)d_out;

    char*  ws  = (char*)d_ws;
    size_t off = 0;
    auto alloc = [&](size_t bytes) -> void* {
        void* p = ws + off;
        off += (bytes + 255) & ~(size_t)255;
        return p;
    };
    float* h      = (float*)alloc((size_t)NB * NN * NF * sizeof(float)); // 102.4 MB
    int*   rs     = (int*)  alloc((size_t)(NN + 1) * sizeof(int));
    int*   cnt    = (int*)  alloc((size_t)NN * sizeof(int));
    int*   cursor = (int*)  alloc((size_t)NN * sizeof(int));
    int*   col_s  = (int*)  alloc((size_t)NE * sizeof(int));
    float* val_s  = (float*)alloc((size_t)NE * sizeof(float));

    hipMemsetAsync(cnt,    0, (size_t)NN * sizeof(int), stream);
    hipMemsetAsync(cursor, 0, (size_t)NN * sizeof(int), stream);

    hist_kernel<<<(NE + 255) / 256, 256, 0, stream>>>(erow, cnt);
    scan_kernel<<<1, 1024, 0, stream>>>(cnt, rs);
    scatter_kernel<<<(NE + 255) / 256, 256, 0, stream>>>(erow, ecol, ev, rs,
                                                         cursor, col_s, val_s);

    const int M = NB * NN;
    gemm_kernel<<<(M + TILE_M - 1) / TILE_M, 256, 0, stream>>>(x, W, h, M);
    spmm_kernel<<<NN, 128, 0, stream>>>(h, rs, col_s, val_s, out);
}

// Round 2
// 427.701 us; speedup vs baseline: 1.5286x; 1.5286x over previous
//
#include <hip/hip_runtime.h>
#include <stdint.h>

// Problem constants (fixed by the reference):
#define NB 4
#define NN 50000
#define NE 800000
#define NF 128

#define NBLK 49          // ceil(NN/1024) for the scan
#define LDK 72           // LDS row stride in bf16 elems: 64 K-chunk + 8 pad

typedef __attribute__((ext_vector_type(8))) short  bfrag;    // 8 bf16 (4 VGPR)
typedef __attribute__((ext_vector_type(4))) float  ffrag;    // 4 fp32 acc
typedef __attribute__((ext_vector_type(4))) short  short4v;  // 8 B LDS store

// fp32 -> bf16 round-to-nearest-even
__device__ inline unsigned short f2bf(float f) {
    unsigned int u = __builtin_bit_cast(unsigned int, f);
    u += 0x7fffu + ((u >> 16) & 1u);
    return (unsigned short)(u >> 16);
}
__device__ inline float bflo(unsigned int u) { return __builtin_bit_cast(float, u << 16); }
__device__ inline float bfhi(unsigned int u) { return __builtin_bit_cast(float, u & 0xffff0000u); }

// ---------------------------------------------------------------------------
// MFMA GEMM: h[n][b][o] = bf16( sum_f x[b*NN+n][f] * W[o][f] )
// 256 thr = 4 waves; block tile 128(M) x 128(N); wave tile 64x64 (4x4 MFMA
// tiles of 16x16x32 bf16). K=128 chunked at 64; fp32->bf16 convert in staging.
// Verified lane maps (guide §3): A[m=lane&15][k=quad*8+j];
// B[k=quad*8+j][n=lane&15]; C/D: col=lane&15, row=quad*4+reg.
// ---------------------------------------------------------------------------
__global__ __launch_bounds__(256) void gemm_kernel(
    const float* __restrict__ x,        // [M][NF] fp32
    const float* __restrict__ W,        // [NF][NF] fp32 (row = out feature)
    unsigned short* __restrict__ h,     // [NN][NB][NF] bf16, node-major
    int M)
{
    __shared__ short xs[128 * LDK];
    __shared__ short wsh[128 * LDK];

    const int tid  = threadIdx.x;
    const int w    = tid >> 6;
    const int lane = tid & 63;
    const int wr   = w >> 1;      // wave row (0..1)
    const int wc   = w & 1;       // wave col (0..1)
    const int q    = lane >> 4;   // quad 0..3
    const int l15  = lane & 15;
    const int m0   = blockIdx.x * 128;

    ffrag acc[4][4];
#pragma unroll
    for (int i = 0; i < 4; ++i)
#pragma unroll
        for (int j = 0; j < 4; ++j) acc[i][j] = (ffrag)0.f;

    for (int kc = 0; kc < 2; ++kc) {
        const int c = kc * 64;
        __syncthreads();
        // stage 128 rows x 64 k of x and W, fp32 -> bf16
#pragma unroll
        for (int it = 0; it < 8; ++it) {
            int linear = it * 256 + tid;   // 0..2047
            int r  = linear >> 4;          // 0..127
            int k4 = linear & 15;          // float4 index (4 k elems)

            float4 wv = *(const float4*)(W + (size_t)r * NF + c + k4 * 4);
            short4v wsv;
            wsv[0] = (short)f2bf(wv.x); wsv[1] = (short)f2bf(wv.y);
            wsv[2] = (short)f2bf(wv.z); wsv[3] = (short)f2bf(wv.w);
            *(short4v*)&wsh[r * LDK + k4 * 4] = wsv;

            int gr = m0 + r;
            float4 xv = make_float4(0.f, 0.f, 0.f, 0.f);
            if (gr < M) xv = *(const float4*)(x + (size_t)gr * NF + c + k4 * 4);
            short4v xsv;
            xsv[0] = (short)f2bf(xv.x); xsv[1] = (short)f2bf(xv.y);
            xsv[2] = (short)f2bf(xv.z); xsv[3] = (short)f2bf(xv.w);
            *(short4v*)&xs[r * LDK + k4 * 4] = xsv;
        }
        __syncthreads();

#pragma unroll
        for (int ks = 0; ks < 2; ++ks) {
            const int ko = ks * 32 + q * 8;   // k offset within chunk
            bfrag a[4], b[4];
#pragma unroll
            for (int i = 0; i < 4; ++i)
                a[i] = *(const bfrag*)&xs[(wr * 64 + i * 16 + l15) * LDK + ko];
#pragma unroll
            for (int j = 0; j < 4; ++j)
                b[j] = *(const bfrag*)&wsh[(wc * 64 + j * 16 + l15) * LDK + ko];
#pragma unroll
            for (int i = 0; i < 4; ++i)
#pragma unroll
                for (int j = 0; j < 4; ++j)
                    acc[i][j] = __builtin_amdgcn_mfma_f32_16x16x32_bf16(
                        a[i], b[j], acc[i][j], 0, 0, 0);
        }
    }

    // epilogue: D(row=q*4+reg, col=l15) per tile; write bf16 node-major
#pragma unroll
    for (int i = 0; i < 4; ++i) {
#pragma unroll
        for (int reg = 0; reg < 4; ++reg) {
            int m = m0 + wr * 64 + i * 16 + q * 4 + reg;
            if (m < M) {
                int n  = m % NN;
                int bb = m / NN;
                unsigned short* hp = h + ((size_t)n * NB + bb) * NF;
#pragma unroll
                for (int j = 0; j < 4; ++j) {
                    int col = wc * 64 + j * 16 + l15;
                    hp[col] = f2bf(acc[i][j][reg]);
                }
            }
        }
    }
}

// ---------------------------------------------------------------------------
// CSR build: histogram -> hierarchical scan (3 small kernels) -> scatter
// ---------------------------------------------------------------------------
__global__ void hist_kernel(const int* __restrict__ row, int* __restrict__ cnt)
{
    int e = blockIdx.x * 256 + threadIdx.x;
    if (e < NE) atomicAdd(&cnt[row[e]], 1);
}

__global__ __launch_bounds__(1024) void scan1_kernel(
    const int* __restrict__ cnt, int* __restrict__ rs, int* __restrict__ bsum)
{
    __shared__ int wsum[16];
    const int tid  = threadIdx.x;
    const int lane = tid & 63;
    const int wid  = tid >> 6;
    const int i    = blockIdx.x * 1024 + tid;

    int v = (i < NN) ? cnt[i] : 0;
    int incl = v;
#pragma unroll
    for (int off = 1; off < 64; off <<= 1) {
        int t = __shfl_up(incl, off, 64);
        if (lane >= off) incl += t;
    }
    if (lane == 63) wsum[wid] = incl;
    __syncthreads();
    int woff = 0;
    for (int ww = 0; ww < wid; ++ww) woff += wsum[ww];
    if (i < NN) rs[i] = woff + incl - v;   // exclusive within block
    if (tid == 0) {
        int tot = 0;
        for (int ww = 0; ww < 16; ++ww) tot += wsum[ww];
        bsum[blockIdx.x] = tot;
    }
}

__global__ void scan2_kernel(int* __restrict__ bsum, int* __restrict__ rs)
{
    int lane = threadIdx.x;   // one wave of 64
    int v = (lane < NBLK) ? bsum[lane] : 0;
    int incl = v;
#pragma unroll
    for (int off = 1; off < 64; off <<= 1) {
        int t = __shfl_up(incl, off, 64);
        if (lane >= off) incl += t;
    }
    if (lane < NBLK) bsum[lane] = incl - v;   // exclusive block offsets
    if (lane == 63) rs[NN] = incl;            // total == NE
}

__global__ __launch_bounds__(1024) void scan3_kernel(
    int* __restrict__ rs, const int* __restrict__ bsum)
{
    int i = blockIdx.x * 1024 + threadIdx.x;
    if (i < NN) rs[i] += bsum[blockIdx.x];
}

__global__ void scatter_kernel(const int* __restrict__ row,
                               const int* __restrict__ col,
                               const float* __restrict__ val,
                               const int* __restrict__ rs,
                               int* __restrict__ cursor,
                               int* __restrict__ col_s,
                               float* __restrict__ val_s)
{
    int e = blockIdx.x * 256 + threadIdx.x;
    if (e < NE) {
        int r   = row[e];
        int p   = atomicAdd(&cursor[r], 1);
        int dst = rs[r] + p;
        col_s[dst] = col[e];
        val_s[dst] = val[e];
    }
}

// ---------------------------------------------------------------------------
// SpMM: wave (64 lanes) per output row; 4 rows per 256-thread block.
// h is bf16 node-major [n][b][f]: one edge = 1 KB contiguous = one
// global_load_dwordx4 per lane. Lane owns batch lane>>4, features (lane&15)*8.
// fp32 accumulate; fully overwrites d_out; no atomics.
// ---------------------------------------------------------------------------
__global__ __launch_bounds__(256) void spmm_kernel(
    const unsigned short* __restrict__ h,   // [NN][NB][NF] bf16
    const int* __restrict__ rs,
    const int* __restrict__ col_s,
    const float* __restrict__ val_s,
    float* __restrict__ out)                // [NB][NN][NF] fp32
{
    const int w    = threadIdx.x >> 6;
    const int lane = threadIdx.x & 63;
    const int r    = blockIdx.x * 4 + w;
    if (r >= NN) return;

    const int s = rs[r];
    const int e = rs[r + 1];
    const int b  = lane >> 4;         // batch 0..3
    const int f0 = (lane & 15) * 8;   // feature start

    float acc[8];
#pragma unroll
    for (int k = 0; k < 8; ++k) acc[k] = 0.f;

    const size_t lane_off = ((size_t)b * NF + f0);   // within a node row

    for (int i = s; i < e; ++i) {
        int   c = col_s[i];
        float v = val_s[i];
        const uint4* hp = (const uint4*)(h + (size_t)c * (NB * NF) + lane_off);
        uint4 qv = *hp;
        acc[0] += v * bflo(qv.x);
        acc[1] += v * bfhi(qv.x);
        acc[2] += v * bflo(qv.y);
        acc[3] += v * bfhi(qv.y);
        acc[4] += v * bflo(qv.z);
        acc[5] += v * bfhi(qv.z);
        acc[6] += v * bflo(qv.w);
        acc[7] += v * bfhi(qv.w);
    }

    float* op = out + ((size_t)b * NN + r) * NF + f0;
    float4 s0 = make_float4(acc[0], acc[1], acc[2], acc[3]);
    float4 s1 = make_float4(acc[4], acc[5], acc[6], acc[7]);
    *(float4*)op       = s0;
    *(float4*)(op + 4) = s1;
}

// ---------------------------------------------------------------------------
extern "C" void kernel_launch(void* const* d_in, const int* in_sizes, int n_in,
                              void* d_out, int out_size, void* d_ws, size_t ws_size,
                              hipStream_t stream)
{
    const float* x    = (const float*)d_in[0];
    const float* W    = (const float*)d_in[1];
    const int*   erow = (const int*)d_in[2];
    const int*   ecol = (const int*)d_in[3];
    const float* ev   = (const float*)d_in[4];
    float*       out  = (float*)d_out;

    char*  ws  = (char*)d_ws;
    size_t off = 0;
    auto alloc = [&](size_t bytes) -> void* {
        void* p = ws + off;
        off += (bytes + 255) & ~(size_t)255;
        return p;
    };
    unsigned short* h = (unsigned short*)alloc((size_t)NN * NB * NF * sizeof(unsigned short)); // 51.2 MB
    int*   rs     = (int*)  alloc((size_t)(NN + 1) * sizeof(int));
    int*   cnt    = (int*)  alloc((size_t)NN * sizeof(int));
    int*   cursor = (int*)  alloc((size_t)NN * sizeof(int));
    int*   bsum   = (int*)  alloc((size_t)64 * sizeof(int));
    int*   col_s  = (int*)  alloc((size_t)NE * sizeof(int));
    float* val_s  = (float*)alloc((size_t)NE * sizeof(float));

    hipMemsetAsync(cnt,    0, (size_t)NN * sizeof(int), stream);
    hipMemsetAsync(cursor, 0, (size_t)NN * sizeof(int), stream);

    const int M = NB * NN;
    gemm_kernel<<<(M + 127) / 128, 256, 0, stream>>>(x, W, h, M);

    hist_kernel<<<(NE + 255) / 256, 256, 0, stream>>>(erow, cnt);
    scan1_kernel<<<NBLK, 1024, 0, stream>>>(cnt, rs, bsum);
    scan2_kernel<<<1, 64, 0, stream>>>(bsum, rs);
    scan3_kernel<<<NBLK, 1024, 0, stream>>>(rs, bsum);
    scatter_kernel<<<(NE + 255) / 256, 256, 0, stream>>>(erow, ecol, ev, rs,
                                                         cursor, col_s, val_s);

    spmm_kernel<<<(NN + 3) / 4, 256, 0, stream>>>(h, rs, col_s, val_s, out);
}

// Round 3
// 422.402 us; speedup vs baseline: 1.5477x; 1.0125x over previous
//
#include <hip/hip_runtime.h>
#include <stdint.h>

// Problem constants (fixed by the reference):
#define NB 4
#define NN 50000
#define NE 800000
#define NF 128

#define NBLK 49          // ceil(NN/1024) for the scan
#define LDK 72           // LDS row stride in bf16 elems: 64 K-chunk + 8 pad

typedef __attribute__((ext_vector_type(8))) short  bfrag;    // 8 bf16 (4 VGPR)
typedef __attribute__((ext_vector_type(4))) float  ffrag;    // 4 fp32 acc
typedef __attribute__((ext_vector_type(4))) short  short4v;  // 8 B LDS store

// fp32 -> bf16 round-to-nearest-even
__device__ inline unsigned short f2bf(float f) {
    unsigned int u = __builtin_bit_cast(unsigned int, f);
    u += 0x7fffu + ((u >> 16) & 1u);
    return (unsigned short)(u >> 16);
}
__device__ inline float bflo(unsigned int u) { return __builtin_bit_cast(float, u << 16); }
__device__ inline float bfhi(unsigned int u) { return __builtin_bit_cast(float, u & 0xffff0000u); }

// ---------------------------------------------------------------------------
// MFMA GEMM: h[n][b][o] = bf16( sum_f x[b*NN+n][f] * W[o][f] )
// 256 thr = 4 waves; block tile 128(M) x 128(N); wave tile 64x64 (4x4 MFMA
// tiles of 16x16x32 bf16). K=128 chunked at 64; fp32->bf16 convert in staging.
// Lane maps (guide §3): A[m=lane&15][k=quad*8+j]; B[k=quad*8+j][n=lane&15];
// C/D: col=lane&15, row=quad*4+reg.
// ---------------------------------------------------------------------------
__global__ __launch_bounds__(256) void gemm_kernel(
    const float* __restrict__ x,        // [M][NF] fp32
    const float* __restrict__ W,        // [NF][NF] fp32 (row = out feature)
    unsigned short* __restrict__ h,     // [NN][NB][NF] bf16, node-major
    int M)
{
    __shared__ short xs[128 * LDK];
    __shared__ short wsh[128 * LDK];

    const int tid  = threadIdx.x;
    const int w    = tid >> 6;
    const int lane = tid & 63;
    const int wr   = w >> 1;      // wave row (0..1)
    const int wc   = w & 1;       // wave col (0..1)
    const int q    = lane >> 4;   // quad 0..3
    const int l15  = lane & 15;
    const int m0   = blockIdx.x * 128;

    ffrag acc[4][4];
#pragma unroll
    for (int i = 0; i < 4; ++i)
#pragma unroll
        for (int j = 0; j < 4; ++j) acc[i][j] = (ffrag)0.f;

    for (int kc = 0; kc < 2; ++kc) {
        const int c = kc * 64;
        __syncthreads();
#pragma unroll
        for (int it = 0; it < 8; ++it) {
            int linear = it * 256 + tid;   // 0..2047
            int r  = linear >> 4;          // 0..127
            int k4 = linear & 15;          // float4 index (4 k elems)

            float4 wv = *(const float4*)(W + (size_t)r * NF + c + k4 * 4);
            short4v wsv;
            wsv[0] = (short)f2bf(wv.x); wsv[1] = (short)f2bf(wv.y);
            wsv[2] = (short)f2bf(wv.z); wsv[3] = (short)f2bf(wv.w);
            *(short4v*)&wsh[r * LDK + k4 * 4] = wsv;

            int gr = m0 + r;
            float4 xv = make_float4(0.f, 0.f, 0.f, 0.f);
            if (gr < M) xv = *(const float4*)(x + (size_t)gr * NF + c + k4 * 4);
            short4v xsv;
            xsv[0] = (short)f2bf(xv.x); xsv[1] = (short)f2bf(xv.y);
            xsv[2] = (short)f2bf(xv.z); xsv[3] = (short)f2bf(xv.w);
            *(short4v*)&xs[r * LDK + k4 * 4] = xsv;
        }
        __syncthreads();

#pragma unroll
        for (int ks = 0; ks < 2; ++ks) {
            const int ko = ks * 32 + q * 8;
            bfrag a[4], b[4];
#pragma unroll
            for (int i = 0; i < 4; ++i)
                a[i] = *(const bfrag*)&xs[(wr * 64 + i * 16 + l15) * LDK + ko];
#pragma unroll
            for (int j = 0; j < 4; ++j)
                b[j] = *(const bfrag*)&wsh[(wc * 64 + j * 16 + l15) * LDK + ko];
#pragma unroll
            for (int i = 0; i < 4; ++i)
#pragma unroll
                for (int j = 0; j < 4; ++j)
                    acc[i][j] = __builtin_amdgcn_mfma_f32_16x16x32_bf16(
                        a[i], b[j], acc[i][j], 0, 0, 0);
        }
    }

#pragma unroll
    for (int i = 0; i < 4; ++i) {
#pragma unroll
        for (int reg = 0; reg < 4; ++reg) {
            int m = m0 + wr * 64 + i * 16 + q * 4 + reg;
            if (m < M) {
                int n  = m % NN;
                int bb = m / NN;
                unsigned short* hp = h + ((size_t)n * NB + bb) * NF;
#pragma unroll
                for (int j = 0; j < 4; ++j) {
                    int col = wc * 64 + j * 16 + l15;
                    hp[col] = f2bf(acc[i][j][reg]);
                }
            }
        }
    }
}

// ---------------------------------------------------------------------------
// CSR build: histogram -> hierarchical scan -> scatter of packed (col,val)
// ---------------------------------------------------------------------------
__global__ void hist_kernel(const int* __restrict__ row, int* __restrict__ cnt)
{
    int e = blockIdx.x * 256 + threadIdx.x;
    if (e < NE) atomicAdd(&cnt[row[e]], 1);
}

__global__ __launch_bounds__(1024) void scan1_kernel(
    const int* __restrict__ cnt, int* __restrict__ rs, int* __restrict__ bsum)
{
    __shared__ int wsum[16];
    const int tid  = threadIdx.x;
    const int lane = tid & 63;
    const int wid  = tid >> 6;
    const int i    = blockIdx.x * 1024 + tid;

    int v = (i < NN) ? cnt[i] : 0;
    int incl = v;
#pragma unroll
    for (int off = 1; off < 64; off <<= 1) {
        int t = __shfl_up(incl, off, 64);
        if (lane >= off) incl += t;
    }
    if (lane == 63) wsum[wid] = incl;
    __syncthreads();
    int woff = 0;
    for (int ww = 0; ww < wid; ++ww) woff += wsum[ww];
    if (i < NN) rs[i] = woff + incl - v;   // exclusive within block
    if (tid == 0) {
        int tot = 0;
        for (int ww = 0; ww < 16; ++ww) tot += wsum[ww];
        bsum[blockIdx.x] = tot;
    }
}

__global__ void scan2_kernel(int* __restrict__ bsum, int* __restrict__ rs)
{
    int lane = threadIdx.x;   // one wave of 64
    int v = (lane < NBLK) ? bsum[lane] : 0;
    int incl = v;
#pragma unroll
    for (int off = 1; off < 64; off <<= 1) {
        int t = __shfl_up(incl, off, 64);
        if (lane >= off) incl += t;
    }
    if (lane < NBLK) bsum[lane] = incl - v;   // exclusive block offsets
    if (lane == 63) rs[NN] = incl;            // total == NE
}

__global__ __launch_bounds__(1024) void scan3_kernel(
    int* __restrict__ rs, const int* __restrict__ bsum, int* __restrict__ cursor)
{
    int i = blockIdx.x * 1024 + threadIdx.x;
    if (i < NN) {
        rs[i] += bsum[blockIdx.x];
        cursor[i] = 0;                        // zero cursor here (saves a memset)
    }
}

__global__ void scatter_kernel(const int* __restrict__ row,
                               const int* __restrict__ col,
                               const float* __restrict__ val,
                               const int* __restrict__ rs,
                               int* __restrict__ cursor,
                               uint2* __restrict__ cv_s)
{
    int e = blockIdx.x * 256 + threadIdx.x;
    if (e < NE) {
        int r   = row[e];
        int p   = atomicAdd(&cursor[r], 1);
        int dst = rs[r] + p;
        uint2 cv;
        cv.x = (unsigned)col[e];
        cv.y = __builtin_bit_cast(unsigned, val[e]);
        cv_s[dst] = cv;                       // single 8 B write per edge
    }
}

// ---------------------------------------------------------------------------
// SpMM: wave per output row (4 rows / 256-thr block). Edge loop unrolled x4:
// 4 independent 1 KB gathers in flight per wave (breaks the latency chain).
// h is bf16 node-major [n][b][f]; lane owns batch lane>>4, feats (lane&15)*8.
// fp32 accumulate; fully overwrites d_out; no atomics.
// ---------------------------------------------------------------------------
__global__ __launch_bounds__(256) void spmm_kernel(
    const unsigned short* __restrict__ h,   // [NN][NB][NF] bf16
    const int* __restrict__ rs,
    const uint2* __restrict__ cv_s,         // packed (col, val)
    float* __restrict__ out)                // [NB][NN][NF] fp32
{
    const int w    = threadIdx.x >> 6;
    const int lane = threadIdx.x & 63;
    const int r    = blockIdx.x * 4 + w;
    if (r >= NN) return;

    const int s = rs[r];
    const int e = rs[r + 1];
    const int b  = lane >> 4;
    const int f0 = (lane & 15) * 8;
    const size_t lane_off = (size_t)b * NF + f0;

    float acc[8];
#pragma unroll
    for (int k = 0; k < 8; ++k) acc[k] = 0.f;

    int i = s;
    for (; i + 4 <= e; i += 4) {
        uint2 cv0 = cv_s[i];
        uint2 cv1 = cv_s[i + 1];
        uint2 cv2 = cv_s[i + 2];
        uint2 cv3 = cv_s[i + 3];
        const uint4 q0 = *(const uint4*)(h + (size_t)cv0.x * (NB * NF) + lane_off);
        const uint4 q1 = *(const uint4*)(h + (size_t)cv1.x * (NB * NF) + lane_off);
        const uint4 q2 = *(const uint4*)(h + (size_t)cv2.x * (NB * NF) + lane_off);
        const uint4 q3 = *(const uint4*)(h + (size_t)cv3.x * (NB * NF) + lane_off);
        float v0 = __builtin_bit_cast(float, cv0.y);
        float v1 = __builtin_bit_cast(float, cv1.y);
        float v2 = __builtin_bit_cast(float, cv2.y);
        float v3 = __builtin_bit_cast(float, cv3.y);
        acc[0] += v0 * bflo(q0.x); acc[1] += v0 * bfhi(q0.x);
        acc[2] += v0 * bflo(q0.y); acc[3] += v0 * bfhi(q0.y);
        acc[4] += v0 * bflo(q0.z); acc[5] += v0 * bfhi(q0.z);
        acc[6] += v0 * bflo(q0.w); acc[7] += v0 * bfhi(q0.w);
        acc[0] += v1 * bflo(q1.x); acc[1] += v1 * bfhi(q1.x);
        acc[2] += v1 * bflo(q1.y); acc[3] += v1 * bfhi(q1.y);
        acc[4] += v1 * bflo(q1.z); acc[5] += v1 * bfhi(q1.z);
        acc[6] += v1 * bflo(q1.w); acc[7] += v1 * bfhi(q1.w);
        acc[0] += v2 * bflo(q2.x); acc[1] += v2 * bfhi(q2.x);
        acc[2] += v2 * bflo(q2.y); acc[3] += v2 * bfhi(q2.y);
        acc[4] += v2 * bflo(q2.z); acc[5] += v2 * bfhi(q2.z);
        acc[6] += v2 * bflo(q2.w); acc[7] += v2 * bfhi(q2.w);
        acc[0] += v3 * bflo(q3.x); acc[1] += v3 * bfhi(q3.x);
        acc[2] += v3 * bflo(q3.y); acc[3] += v3 * bfhi(q3.y);
        acc[4] += v3 * bflo(q3.z); acc[5] += v3 * bfhi(q3.z);
        acc[6] += v3 * bflo(q3.w); acc[7] += v3 * bfhi(q3.w);
    }
    for (; i < e; ++i) {
        uint2 cv = cv_s[i];
        float v  = __builtin_bit_cast(float, cv.y);
        const uint4 qv = *(const uint4*)(h + (size_t)cv.x * (NB * NF) + lane_off);
        acc[0] += v * bflo(qv.x); acc[1] += v * bfhi(qv.x);
        acc[2] += v * bflo(qv.y); acc[3] += v * bfhi(qv.y);
        acc[4] += v * bflo(qv.z); acc[5] += v * bfhi(qv.z);
        acc[6] += v * bflo(qv.w); acc[7] += v * bfhi(qv.w);
    }

    float* op = out + ((size_t)b * NN + r) * NF + f0;
    *(float4*)op       = make_float4(acc[0], acc[1], acc[2], acc[3]);
    *(float4*)(op + 4) = make_float4(acc[4], acc[5], acc[6], acc[7]);
}

// ---------------------------------------------------------------------------
extern "C" void kernel_launch(void* const* d_in, const int* in_sizes, int n_in,
                              void* d_out, int out_size, void* d_ws, size_t ws_size,
                              hipStream_t stream)
{
    const float* x    = (const float*)d_in[0];
    const float* W    = (const float*)d_in[1];
    const int*   erow = (const int*)d_in[2];
    const int*   ecol = (const int*)d_in[3];
    const float* ev   = (const float*)d_in[4];
    float*       out  = (float*)d_out;

    char*  ws  = (char*)d_ws;
    size_t off = 0;
    auto alloc = [&](size_t bytes) -> void* {
        void* p = ws + off;
        off += (bytes + 255) & ~(size_t)255;
        return p;
    };
    unsigned short* h = (unsigned short*)alloc((size_t)NN * NB * NF * sizeof(unsigned short)); // 51.2 MB
    int*   rs     = (int*)  alloc((size_t)(NN + 1) * sizeof(int));
    int*   cnt    = (int*)  alloc((size_t)NN * sizeof(int));
    int*   cursor = (int*)  alloc((size_t)NN * sizeof(int));
    int*   bsum   = (int*)  alloc((size_t)64 * sizeof(int));
    uint2* cv_s   = (uint2*)alloc((size_t)NE * sizeof(uint2));

    hipMemsetAsync(cnt, 0, (size_t)NN * sizeof(int), stream);

    const int M = NB * NN;
    gemm_kernel<<<(M + 127) / 128, 256, 0, stream>>>(x, W, h, M);

    hist_kernel<<<(NE + 255) / 256, 256, 0, stream>>>(erow, cnt);
    scan1_kernel<<<NBLK, 1024, 0, stream>>>(cnt, rs, bsum);
    scan2_kernel<<<1, 64, 0, stream>>>(bsum, rs);
    scan3_kernel<<<NBLK, 1024, 0, stream>>>(rs, bsum, cursor);
    scatter_kernel<<<(NE + 255) / 256, 256, 0, stream>>>(erow, ecol, ev, rs,
                                                         cursor, cv_s);

    spmm_kernel<<<(NN + 3) / 4, 256, 0, stream>>>(h, rs, cv_s, out);
}

// Round 4
// 406.014 us; speedup vs baseline: 1.6102x; 1.0404x over previous
//
#include <hip/hip_runtime.h>
#include <stdint.h>

// Problem constants (fixed by the reference):
#define NB 4
#define NN 50000
#define NE 800000
#define NF 128

#define NBLK 49          // ceil(NN/1024) for the scan
#define LDK 72           // LDS row stride in bf16 elems: 64 K-chunk + 8 pad
#define LDT 136          // epilogue tile row stride (128 + 8 pad)

typedef __attribute__((ext_vector_type(8))) short  bfrag;    // 8 bf16 (4 VGPR)
typedef __attribute__((ext_vector_type(4))) float  ffrag;    // 4 fp32 acc
typedef __attribute__((ext_vector_type(4))) short  short4v;  // 8 B LDS store

// fp32 -> bf16 round-to-nearest-even
__device__ inline unsigned short f2bf(float f) {
    unsigned int u = __builtin_bit_cast(unsigned int, f);
    u += 0x7fffu + ((u >> 16) & 1u);
    return (unsigned short)(u >> 16);
}
__device__ inline float bflo(unsigned int u) { return __builtin_bit_cast(float, u << 16); }
__device__ inline float bfhi(unsigned int u) { return __builtin_bit_cast(float, u & 0xffff0000u); }

// ---------------------------------------------------------------------------
// MFMA GEMM (+fused edge histogram): h[n][b][o] = bf16(sum_f x[m][f]*W[o][f])
// 256 thr = 4 waves; block tile 128x128; wave tile 64x64 (4x4 of 16x16x32).
// Histogram atomics issued first — they overlap the memory-bound GEMM.
// Epilogue repacks C through LDS -> coalesced dwordx4 stores (was 64 scalar
// 2 B global stores per thread).
// ---------------------------------------------------------------------------
__global__ __launch_bounds__(256) void gemm_kernel(
    const float* __restrict__ x,        // [M][NF] fp32
    const float* __restrict__ W,        // [NF][NF] fp32 (row = out feature)
    unsigned short* __restrict__ h,     // [NN][NB][NF] bf16, node-major
    const int* __restrict__ erow,       // fused histogram input
    int* __restrict__ cnt,              // fused histogram output (pre-zeroed)
    int M)
{
    __shared__ short smem[2 * 128 * LDK];   // 36 KiB; reused by epilogue
    short* xs  = smem;
    short* wsh = smem + 128 * LDK;

    const int tid  = threadIdx.x;

    // --- fused histogram (overlaps with GEMM main loop) ---
    for (int e = blockIdx.x * 256 + tid; e < NE; e += gridDim.x * 256)
        atomicAdd(&cnt[erow[e]], 1);

    const int w    = tid >> 6;
    const int lane = tid & 63;
    const int wr   = w >> 1;      // wave row (0..1)
    const int wc   = w & 1;       // wave col (0..1)
    const int q    = lane >> 4;   // quad 0..3
    const int l15  = lane & 15;
    const int m0   = blockIdx.x * 128;

    ffrag acc[4][4];
#pragma unroll
    for (int i = 0; i < 4; ++i)
#pragma unroll
        for (int j = 0; j < 4; ++j) acc[i][j] = (ffrag)0.f;

    for (int kc = 0; kc < 2; ++kc) {
        const int c = kc * 64;
        __syncthreads();
#pragma unroll
        for (int it = 0; it < 8; ++it) {
            int linear = it * 256 + tid;   // 0..2047
            int r  = linear >> 4;          // 0..127
            int k4 = linear & 15;          // float4 index (4 k elems)

            float4 wv = *(const float4*)(W + (size_t)r * NF + c + k4 * 4);
            short4v wsv;
            wsv[0] = (short)f2bf(wv.x); wsv[1] = (short)f2bf(wv.y);
            wsv[2] = (short)f2bf(wv.z); wsv[3] = (short)f2bf(wv.w);
            *(short4v*)&wsh[r * LDK + k4 * 4] = wsv;

            int gr = m0 + r;
            float4 xv = make_float4(0.f, 0.f, 0.f, 0.f);
            if (gr < M) xv = *(const float4*)(x + (size_t)gr * NF + c + k4 * 4);
            short4v xsv;
            xsv[0] = (short)f2bf(xv.x); xsv[1] = (short)f2bf(xv.y);
            xsv[2] = (short)f2bf(xv.z); xsv[3] = (short)f2bf(xv.w);
            *(short4v*)&xs[r * LDK + k4 * 4] = xsv;
        }
        __syncthreads();

#pragma unroll
        for (int ks = 0; ks < 2; ++ks) {
            const int ko = ks * 32 + q * 8;
            bfrag a[4], b[4];
#pragma unroll
            for (int i = 0; i < 4; ++i)
                a[i] = *(const bfrag*)&xs[(wr * 64 + i * 16 + l15) * LDK + ko];
#pragma unroll
            for (int j = 0; j < 4; ++j)
                b[j] = *(const bfrag*)&wsh[(wc * 64 + j * 16 + l15) * LDK + ko];
#pragma unroll
            for (int i = 0; i < 4; ++i)
#pragma unroll
                for (int j = 0; j < 4; ++j)
                    acc[i][j] = __builtin_amdgcn_mfma_f32_16x16x32_bf16(
                        a[i], b[j], acc[i][j], 0, 0, 0);
        }
    }

    // --- epilogue: repack through LDS, then coalesced 16 B stores ---
    __syncthreads();                      // done with xs/wsh
    short* tile = smem;                   // [128][LDT] bf16 (34 KiB)
#pragma unroll
    for (int i = 0; i < 4; ++i)
#pragma unroll
        for (int reg = 0; reg < 4; ++reg) {
            int row = wr * 64 + i * 16 + q * 4 + reg;
#pragma unroll
            for (int j = 0; j < 4; ++j)
                tile[row * LDT + wc * 64 + j * 16 + l15] =
                    (short)f2bf(acc[i][j][reg]);
        }
    __syncthreads();
#pragma unroll
    for (int it = 0; it < 8; ++it) {
        int row = it * 16 + (tid >> 4);
        int m   = m0 + row;
        if (m < M) {
            int n  = m % NN;
            int bb = m / NN;
            uint4 v = *(const uint4*)&tile[row * LDT + (tid & 15) * 8];
            *(uint4*)(h + ((size_t)n * NB + bb) * NF + (tid & 15) * 8) = v;
        }
    }
}

// ---------------------------------------------------------------------------
// CSR build: scan1 (per-1024-block exclusive) -> scan2 (block offsets).
// scan3 is folded into scatter/spmm (they add bsum[r>>10] on the fly).
// ---------------------------------------------------------------------------
__global__ __launch_bounds__(1024) void scan1_kernel(
    const int* __restrict__ cnt, int* __restrict__ rs, int* __restrict__ bsum)
{
    __shared__ int wsum[16];
    const int tid  = threadIdx.x;
    const int lane = tid & 63;
    const int wid  = tid >> 6;
    const int i    = blockIdx.x * 1024 + tid;

    int v = (i < NN) ? cnt[i] : 0;
    int incl = v;
#pragma unroll
    for (int off = 1; off < 64; off <<= 1) {
        int t = __shfl_up(incl, off, 64);
        if (lane >= off) incl += t;
    }
    if (lane == 63) wsum[wid] = incl;
    __syncthreads();
    int woff = 0;
    for (int ww = 0; ww < wid; ++ww) woff += wsum[ww];
    if (i < NN) rs[i] = woff + incl - v;   // exclusive within block
    if (tid == 0) {
        int tot = 0;
        for (int ww = 0; ww < 16; ++ww) tot += wsum[ww];
        bsum[blockIdx.x] = tot;
    }
}

__global__ void scan2_kernel(int* __restrict__ bsum)
{
    int lane = threadIdx.x;   // one wave of 64
    int v = (lane < NBLK) ? bsum[lane] : 0;
    int incl = v;
#pragma unroll
    for (int off = 1; off < 64; off <<= 1) {
        int t = __shfl_up(incl, off, 64);
        if (lane >= off) incl += t;
    }
    if (lane < NBLK) bsum[lane] = incl - v;   // exclusive block offsets
}

__global__ void scatter_kernel(const int* __restrict__ row,
                               const int* __restrict__ col,
                               const float* __restrict__ val,
                               const int* __restrict__ rs,
                               const int* __restrict__ bsum,
                               int* __restrict__ cursor,
                               uint2* __restrict__ cv_s)
{
    int e = blockIdx.x * 256 + threadIdx.x;
    if (e < NE) {
        int r   = row[e];
        int p   = atomicAdd(&cursor[r], 1);
        int dst = rs[r] + bsum[r >> 10] + p;
        uint2 cv;
        cv.x = (unsigned)col[e];
        cv.y = __builtin_bit_cast(unsigned, val[e]);
        cv_s[dst] = cv;                       // single 8 B write per edge
    }
}

// ---------------------------------------------------------------------------
// SpMM: wave per output row (4 rows / 256-thr block), x4 unrolled gathers.
// h is bf16 node-major [n][b][f]; lane owns batch lane>>4, feats (lane&15)*8.
// fp32 accumulate; fully overwrites d_out; no atomics.
// ---------------------------------------------------------------------------
__global__ __launch_bounds__(256) void spmm_kernel(
    const unsigned short* __restrict__ h,   // [NN][NB][NF] bf16
    const int* __restrict__ rs,
    const int* __restrict__ bsum,
    const uint2* __restrict__ cv_s,         // packed (col, val)
    float* __restrict__ out)                // [NB][NN][NF] fp32
{
    const int w    = threadIdx.x >> 6;
    const int lane = threadIdx.x & 63;
    const int r    = blockIdx.x * 4 + w;
    if (r >= NN) return;

    const int s = rs[r] + bsum[r >> 10];
    const int e = (r + 1 == NN) ? NE : rs[r + 1] + bsum[(r + 1) >> 10];
    const int b  = lane >> 4;
    const int f0 = (lane & 15) * 8;
    const size_t lane_off = (size_t)b * NF + f0;

    float acc[8];
#pragma unroll
    for (int k = 0; k < 8; ++k) acc[k] = 0.f;

    int i = s;
    for (; i + 4 <= e; i += 4) {
        uint2 cv0 = cv_s[i];
        uint2 cv1 = cv_s[i + 1];
        uint2 cv2 = cv_s[i + 2];
        uint2 cv3 = cv_s[i + 3];
        const uint4 q0 = *(const uint4*)(h + (size_t)cv0.x * (NB * NF) + lane_off);
        const uint4 q1 = *(const uint4*)(h + (size_t)cv1.x * (NB * NF) + lane_off);
        const uint4 q2 = *(const uint4*)(h + (size_t)cv2.x * (NB * NF) + lane_off);
        const uint4 q3 = *(const uint4*)(h + (size_t)cv3.x * (NB * NF) + lane_off);
        float v0 = __builtin_bit_cast(float, cv0.y);
        float v1 = __builtin_bit_cast(float, cv1.y);
        float v2 = __builtin_bit_cast(float, cv2.y);
        float v3 = __builtin_bit_cast(float, cv3.y);
        acc[0] += v0 * bflo(q0.x); acc[1] += v0 * bfhi(q0.x);
        acc[2] += v0 * bflo(q0.y); acc[3] += v0 * bfhi(q0.y);
        acc[4] += v0 * bflo(q0.z); acc[5] += v0 * bfhi(q0.z);
        acc[6] += v0 * bflo(q0.w); acc[7] += v0 * bfhi(q0.w);
        acc[0] += v1 * bflo(q1.x); acc[1] += v1 * bfhi(q1.x);
        acc[2] += v1 * bflo(q1.y); acc[3] += v1 * bfhi(q1.y);
        acc[4] += v1 * bflo(q1.z); acc[5] += v1 * bfhi(q1.z);
        acc[6] += v1 * bflo(q1.w); acc[7] += v1 * bfhi(q1.w);
        acc[0] += v2 * bflo(q2.x); acc[1] += v2 * bfhi(q2.x);
        acc[2] += v2 * bflo(q2.y); acc[3] += v2 * bfhi(q2.y);
        acc[4] += v2 * bflo(q2.z); acc[5] += v2 * bfhi(q2.z);
        acc[6] += v2 * bflo(q2.w); acc[7] += v2 * bfhi(q2.w);
        acc[0] += v3 * bflo(q3.x); acc[1] += v3 * bfhi(q3.x);
        acc[2] += v3 * bflo(q3.y); acc[3] += v3 * bfhi(q3.y);
        acc[4] += v3 * bflo(q3.z); acc[5] += v3 * bfhi(q3.z);
        acc[6] += v3 * bflo(q3.w); acc[7] += v3 * bfhi(q3.w);
    }
    for (; i < e; ++i) {
        uint2 cv = cv_s[i];
        float v  = __builtin_bit_cast(float, cv.y);
        const uint4 qv = *(const uint4*)(h + (size_t)cv.x * (NB * NF) + lane_off);
        acc[0] += v * bflo(qv.x); acc[1] += v * bfhi(qv.x);
        acc[2] += v * bflo(qv.y); acc[3] += v * bfhi(qv.y);
        acc[4] += v * bflo(qv.z); acc[5] += v * bfhi(qv.z);
        acc[6] += v * bflo(qv.w); acc[7] += v * bfhi(qv.w);
    }

    float* op = out + ((size_t)b * NN + r) * NF + f0;
    *(float4*)op       = make_float4(acc[0], acc[1], acc[2], acc[3]);
    *(float4*)(op + 4) = make_float4(acc[4], acc[5], acc[6], acc[7]);
}

// ---------------------------------------------------------------------------
extern "C" void kernel_launch(void* const* d_in, const int* in_sizes, int n_in,
                              void* d_out, int out_size, void* d_ws, size_t ws_size,
                              hipStream_t stream)
{
    const float* x    = (const float*)d_in[0];
    const float* W    = (const float*)d_in[1];
    const int*   erow = (const int*)d_in[2];
    const int*   ecol = (const int*)d_in[3];
    const float* ev   = (const float*)d_in[4];
    float*       out  = (float*)d_out;

    char*  ws  = (char*)d_ws;
    size_t off = 0;
    auto alloc = [&](size_t bytes) -> void* {
        void* p = ws + off;
        off += (bytes + 255) & ~(size_t)255;
        return p;
    };
    unsigned short* h = (unsigned short*)alloc((size_t)NN * NB * NF * sizeof(unsigned short)); // 51.2 MB
    int*   rs     = (int*)  alloc((size_t)(NN + 1) * sizeof(int));
    int*   cnt    = (int*)  alloc((size_t)2 * NN * sizeof(int));  // cnt + cursor, contiguous
    int*   cursor = cnt + NN;
    int*   bsum   = (int*)  alloc((size_t)64 * sizeof(int));
    uint2* cv_s   = (uint2*)alloc((size_t)NE * sizeof(uint2));

    hipMemsetAsync(cnt, 0, (size_t)2 * NN * sizeof(int), stream);  // cnt + cursor

    const int M = NB * NN;
    gemm_kernel<<<(M + 127) / 128, 256, 0, stream>>>(x, W, h, erow, cnt, M);

    scan1_kernel<<<NBLK, 1024, 0, stream>>>(cnt, rs, bsum);
    scan2_kernel<<<1, 64, 0, stream>>>(bsum);
    scatter_kernel<<<(NE + 255) / 256, 256, 0, stream>>>(erow, ecol, ev, rs,
                                                         bsum, cursor, cv_s);

    spmm_kernel<<<(NN + 3) / 4, 256, 0, stream>>>(h, rs, bsum, cv_s, out);
}